// Round 6
// baseline (2425.779 us; speedup 1.0000x reference)
//
#include <hip/hip_runtime.h>

// ---------------------------------------------------------------------------
// Fused decoder: B=8192 x 40 steps, one WG of 1024 threads (16 waves) per 32
// rows, grid=256 (1 WG/CU, 4 waves/SIMD). 16x16x32 bf16 MFMA.
// R6: __launch_bounds__(1024,4) -> 128-VGPR budget; sched_barrier(0)-pinned
// preload batches (loads physically cannot sink to their use) give real MLP:
// gates GEMM runs a depth-3 rotating weight pipeline (8 loads in flight),
// every other phase batch-preloads its weights. Step-invariant biases hoisted.
// Raw lgkmcnt-only barriers keep vmem in flight across phases.
// ---------------------------------------------------------------------------

#define BDIM  8192
#define HDIM  256
#define FDIM  128
#define ZDIM  64
#define TDIM  43
#define STEPS 40

typedef __attribute__((ext_vector_type(8))) __bf16 bf16x8;
typedef __attribute__((ext_vector_type(4))) float  f32x4;

// LDS activation buffer (cols are bf16 elements)
#define ACT_STRIDE 3248   // bytes/row; 812 dw == 12 (mod 32), +16B stagger per 8 rows
#define C_Z   0           // z          (64)
#define C_Y0  64          // y parity 0 (128)
#define C_Y1  192         // y parity 1 (128)
#define C_H0  320         // h parity 0 (256)
#define C_H1  576         // h parity 1 (256)
#define C_C   832         // c_new      (256)   (holds h_i during startup folds)
#define C_T0  1088        // y1         (128)
#define C_T1  1216        // y2         (128)
#define C_HZ  1344        // hz  (inf)  (64)
#define C_HZP 1408        // hzp (prior)(64)
#define C_B4  1472        // h_i@w4+b4 fold, bf16 (64)
#define C_B7  1536        // h_i@w7+b7 fold, bf16 (64)  -> 1600 cols

// packed-weight offsets in __bf16 elements
#define PW_GS  0u         // gates [z|yp|h] K=448 N=1024 (KT=14)
#define PW_GHI 458752u    // gates h_i part K=256 N=1024 (KT=8)
#define PW_W1  720896u    // K=256 N=128 (KT=8)
#define PW_W2  753664u    // K=128 N=128 (KT=4)
#define PW_W3  770048u    // K=128 N=128 (KT=4)
#define PW_W4S 786432u    // w4 rows 256:768 [c|y|yp] K=512 N=64 (KT=16)
#define PW_W4H 819200u    // w4 rows 0:256 K=256 N=64 (KT=8)
#define PW_W5  835584u    // K=64 N=64 (KT=2)
#define PW_W6  839680u
#define PW_W7S 843776u    // w7 rows 256:640 [c|yp] K=384 N=64 (KT=12)
#define PW_W7H 868352u    // w7 rows 0:256 K=256 N=64 (KT=8)
#define PW_W8  884736u
#define PW_W9  888832u

#define SB() __builtin_amdgcn_sched_barrier(0)

__device__ __forceinline__ int act_off(int row, int col) {
  return row * ACT_STRIDE + ((row >> 3) << 4) + (col << 1);
}
__device__ __forceinline__ f32x4 mfma16(bf16x8 a, bf16x8 b, f32x4 c) {
  return __builtin_amdgcn_mfma_f32_16x16x32_bf16(a, b, c, 0, 0, 0);
}
__device__ __forceinline__ float sigm(float x) { return 1.f / (1.f + __expf(-x)); }
__device__ __forceinline__ float tanh_f(float x) {
  float t = __expf(-2.f * fabsf(x));
  float r = (1.f - t) / (1.f + t);
  return x < 0.f ? -r : r;
}
// LDS-drain-only barrier: weight/eps loads + output stores (vmcnt) stay in
// flight across phases; LDS producer->consumer ordering is preserved.
__device__ __forceinline__ void wg_barrier() {
  asm volatile("s_waitcnt lgkmcnt(0)" ::: "memory");
  __builtin_amdgcn_s_barrier();
  __builtin_amdgcn_sched_barrier(0);
}
// A-fragment read: lane l holds A[mt*16 + (l&15)][k = (l>>4)*8 + j]
__device__ __forceinline__ bf16x8 aread(const unsigned char* actb, int mt, int col,
                                        int lane) {
  return *(const bf16x8*)(actb + act_off(mt * 16 + (lane & 15), col + ((lane >> 4) << 3)));
}
// C-fragment store with bias+relu: row = mt*16 + (lane>>4)*4 + r
__device__ __forceinline__ void st16(unsigned char* actb, int col, int mt, int rsub,
                                     f32x4 v, float bv) {
#pragma unroll
  for (int r = 0; r < 4; ++r)
    *(__bf16*)(actb + act_off(mt * 16 + rsub + r, col)) = (__bf16)fmaxf(v[r] + bv, 0.f);
}
__device__ __forceinline__ unsigned int pk2(float a, float b) {
  union { __bf16 h; unsigned short u; } x, y;
  x.h = (__bf16)a; y.h = (__bf16)b;
  return (unsigned int)x.u | ((unsigned int)y.u << 16);
}
__device__ __forceinline__ float upkf(unsigned int u, int hi) {
  union { unsigned int i; float f; } c;
  c.i = hi ? (u & 0xffff0000u) : (u << 16);
  return c.f;
}

// ---------------------------------------------------------------------------
// Pack (up to 3 K-stacked row segments) into 16-wide B-fragments:
// frag f=(nt*KT+kt)*64+lane holds W[kt*32+(lane>>4)*8+j][nt*16+(lane&15)].
// ---------------------------------------------------------------------------
struct PSeg { const float* p; int row0; int len; };

__global__ __launch_bounds__(256) void pack_w(PSeg s0, PSeg s1, PSeg s2,
                                              int K, int N, __bf16* __restrict__ dst) {
  int f = blockIdx.x * 256 + threadIdx.x;
  int KT = K >> 5;
  int total = KT * (N >> 4) * 64;
  if (f >= total) return;
  int lane = f & 63;
  int tile = f >> 6;
  int kt = tile % KT;
  int nt = tile / KT;
  int k0 = kt * 32 + ((lane >> 4) << 3);
  int n = (nt << 4) + (lane & 15);
  bf16x8 v;
#pragma unroll
  for (int j = 0; j < 8; ++j) {
    int k = k0 + j;
    const float* src;
    int r;
    if (k < s0.len) { src = s0.p; r = s0.row0 + k; }
    else if (k < s0.len + s1.len) { src = s1.p; r = s1.row0 + (k - s0.len); }
    else { src = s2.p; r = s2.row0 + (k - s0.len - s1.len); }
    v[j] = (__bf16)src[(size_t)r * N + n];
  }
  *(bf16x8*)(dst + (size_t)f * 8) = v;
}

struct Params {
  const float *h_i, *input_t, *eps_inf, *eps_prior;
  const float *b_lstm, *b1, *b2, *b3, *b4, *b5, *b6, *b7, *b8, *b9;
  const float *alpha, *beta, *mu0;
  const __bf16* wpack;
  float* out;
};

// load one kt-slice (4 gate fragments) of the gates weights into wb[t]
#define LDK(t, ktv)                                                         \
  do {                                                                      \
    _Pragma("unroll") for (int g = 0; g < 4; ++g) wb[t][g] =                \
        wgs[((size_t)(g * 16 + w) * 14 + (ktv)) * 64 + lane];               \
  } while (0)

__global__ __launch_bounds__(1024, 4) void decoder_main(Params p) {
  __shared__ __align__(16) unsigned char act[32 * ACT_STRIDE];  // 103936 B
  __shared__ float fbuf[2048];                                  // 8192 B
  __shared__ float inten[STEPS * 32];                           // 5120 B

  const int tid = threadIdx.x;
  const int w = tid >> 6;
  const int lane = tid & 63;
  const int ln16 = lane & 15;
  const int rsub = (lane >> 4) << 2;
  const int r0 = blockIdx.x * 32;

  for (int i = tid; i < (32 * ACT_STRIDE) / 4; i += 1024) ((unsigned int*)act)[i] = 0u;
  __syncthreads();
  // stage h_i bf16 into C_C (consumed by the startup folds only)
  for (int i = tid; i < 32 * 256; i += 1024) {
    int row = i >> 8, col = i & 255;
    *(__bf16*)(act + act_off(row, C_C + col)) =
        (__bf16)p.h_i[(size_t)(r0 + row) * HDIM + col];
  }
  {
    float ab = p.alpha[0] * p.beta[0], mu = p.mu0[0];
    for (int t = tid; t < 32 * STEPS; t += 1024) {
      int row = t & 31, j = t >> 5;
      const float* tp = p.input_t + (size_t)(r0 + row) * TDIM;
      float tc = tp[j + 3];
      float s = 0.f;
      for (int idx = 0; idx < j + 3; ++idx) s += __expf(tp[idx] - tc);
      inten[j * 32 + row] = mu + ab * s;
    }
  }
  __syncthreads();

  const __bf16* W = p.wpack;
  const bf16x8* wgs = (const bf16x8*)(W + PW_GS);
  const bf16x8* wghi = (const bf16x8*)(W + PW_GHI);
  const bf16x8* w1p = (const bf16x8*)(W + PW_W1);
  const bf16x8* w2p = (const bf16x8*)(W + PW_W2);
  const bf16x8* w3p = (const bf16x8*)(W + PW_W3);
  const bf16x8* w4s = (const bf16x8*)(W + PW_W4S);
  const bf16x8* w4h = (const bf16x8*)(W + PW_W4H);
  const bf16x8* w5p = (const bf16x8*)(W + PW_W5);
  const bf16x8* w6p = (const bf16x8*)(W + PW_W6);
  const bf16x8* w7s = (const bf16x8*)(W + PW_W7S);
  const bf16x8* w7h = (const bf16x8*)(W + PW_W7H);
  const bf16x8* w8p = (const bf16x8*)(W + PW_W8);
  const bf16x8* w9p = (const bf16x8*)(W + PW_W9);

  // ---- startup folds ----
  uint2 gbp[4][2];  // h_i@Wx_hi + b_lstm, packed bf16 per gate/mtile
  {
    f32x4 g[4][2] = {};
#pragma unroll
    for (int kt = 0; kt < 8; ++kt) {
      bf16x8 a0 = aread(act, 0, C_C + kt * 32, lane);
      bf16x8 a1 = aread(act, 1, C_C + kt * 32, lane);
#pragma unroll
      for (int gg = 0; gg < 4; ++gg) {
        bf16x8 b = wghi[((size_t)(gg * 16 + w) * 8 + kt) * 64 + lane];
        g[gg][0] = mfma16(a0, b, g[gg][0]);
        g[gg][1] = mfma16(a1, b, g[gg][1]);
      }
    }
#pragma unroll
    for (int gg = 0; gg < 4; ++gg) {
      float bv = p.b_lstm[gg * 256 + w * 16 + ln16];
#pragma unroll
      for (int mt = 0; mt < 2; ++mt) {
        gbp[gg][mt].x = pk2(g[gg][mt][0] + bv, g[gg][mt][1] + bv);
        gbp[gg][mt].y = pk2(g[gg][mt][2] + bv, g[gg][mt][3] + bv);
      }
    }
  }
  {  // h_i@w4h+b4 -> C_B4 (waves 0-7); h_i@w7h+b7 -> C_B7 (waves 8-15)
    int n = w & 3, mt = (w >> 2) & 1;
    const bf16x8* wp = (w < 8) ? w4h : w7h;
    const float* bb = (w < 8) ? p.b4 : p.b7;
    int cb = (w < 8) ? C_B4 : C_B7;
    f32x4 v = {};
#pragma unroll
    for (int kt = 0; kt < 8; ++kt)
      v = mfma16(aread(act, mt, C_C + kt * 32, lane),
                 wp[(size_t)(n * 8 + kt) * 64 + lane], v);
    float bv = bb[n * 16 + ln16];
#pragma unroll
    for (int r = 0; r < 4; ++r)
      *(__bf16*)(act + act_off(mt * 16 + rsub + r, cb + n * 16 + ln16)) =
          (__bf16)(v[r] + bv);
  }
  f32x4 c_st[2] = {};

  // ---- step-invariant bias hoists (per wave role) ----
  float bv1 = 0.f, bv2 = 0.f, bv3 = 0.f, bmA = 0.f, blA = 0.f;
  {
    int n = w & 3;
    if (w < 8) {
      bv1 = p.b1[w * 16 + ln16];
      bv2 = p.b2[w * 16 + ln16];
      bv3 = p.b3[w * 16 + ln16];
      bmA = p.b5[n * 16 + ln16];  // mean_j
      blA = p.b6[n * 16 + ln16];  // lv_j
    } else {
      bmA = p.b8[n * 16 + ln16];  // mean_p
      blA = p.b9[n * 16 + ln16];  // lv_p
    }
  }
  __syncthreads();

  float* outy = p.out;
  float* outm = p.out + (size_t)BDIM * STEPS * FDIM;
  float* outl = outm + (size_t)BDIM * STEPS * ZDIM;
  float* outz = outl + (size_t)BDIM * STEPS * ZDIM;
  float* outzp = outz + (size_t)BDIM * STEPS * ZDIM;

  // rotating depth-3 gates-weight prefetch, kept warm across steps
  bf16x8 wb[3][4];
  LDK(0, 0);
  LDK(1, 1);
  LDK(2, 2);
  SB();

  for (int j = 0; j < STEPS; ++j) {
    const int yW = (j & 1) ? C_Y1 : C_Y0, yR = (j & 1) ? C_Y0 : C_Y1;
    const int hW = (j & 1) ? C_H1 : C_H0, hR = (j & 1) ? C_H0 : C_H1;

    // ---- A: gates = [z|yp|h]@Wgs + gb; wave w owns cols w*16 of all 4 gates
    // depth-3 register pipeline; per-iteration sched_barrier pins the refill
    // in its own iteration (8 weight loads stay in flight).
    {
      f32x4 acc[4][2] = {};
#pragma unroll
      for (int kt = 0; kt < 14; ++kt) {
        int col = (kt < 2) ? (C_Z + kt * 32)
                           : (kt < 6) ? (yR + (kt - 2) * 32) : (hR + (kt - 6) * 32);
        bf16x8 a0 = aread(act, 0, col, lane);
        bf16x8 a1 = aread(act, 1, col, lane);
        const int s = kt % 3;
#pragma unroll
        for (int g = 0; g < 4; ++g) {
          acc[g][0] = mfma16(a0, wb[s][g], acc[g][0]);
          acc[g][1] = mfma16(a1, wb[s][g], acc[g][1]);
        }
        if (kt + 3 < 14) LDK(s, kt + 3);
        SB();
      }
#pragma unroll
      for (int mt = 0; mt < 2; ++mt) {
#pragma unroll
        for (int r = 0; r < 4; ++r) {
          int row = mt * 16 + rsub + r;
          unsigned int ui = (r < 2) ? gbp[0][mt].x : gbp[0][mt].y;
          unsigned int uf = (r < 2) ? gbp[1][mt].x : gbp[1][mt].y;
          unsigned int ug = (r < 2) ? gbp[2][mt].x : gbp[2][mt].y;
          unsigned int uo = (r < 2) ? gbp[3][mt].x : gbp[3][mt].y;
          float ig = sigm(acc[0][mt][r] + upkf(ui, r & 1));
          float fg = sigm(acc[1][mt][r] + upkf(uf, r & 1));
          float gg = tanh_f(acc[2][mt][r] + upkf(ug, r & 1));
          float og = sigm(acc[3][mt][r] + upkf(uo, r & 1));
          float cn = fg * c_st[mt][r] + ig * gg;
          float hn = og * tanh_f(cn);
          c_st[mt][r] = inten[j * 32 + row] * cn;
          *(__bf16*)(act + act_off(row, C_C + w * 16 + ln16)) = (__bf16)cn;
          *(__bf16*)(act + act_off(row, hW + w * 16 + ln16)) = (__bf16)hn;
        }
      }
    }
    wg_barrier();

    // ---- B: w0-7 y1 = relu(h@w1+b1); w8-15 full-K prior -> hzp
    if (w < 8) {
      bf16x8 wf[8];
#pragma unroll
      for (int kt = 0; kt < 8; ++kt) wf[kt] = w1p[(size_t)(w * 8 + kt) * 64 + lane];
      SB();
      f32x4 a0 = {}, a1 = {};
#pragma unroll
      for (int kt = 0; kt < 8; ++kt) {
        a0 = mfma16(aread(act, 0, hW + kt * 32, lane), wf[kt], a0);
        a1 = mfma16(aread(act, 1, hW + kt * 32, lane), wf[kt], a1);
      }
      st16(act, C_T0 + w * 16 + ln16, 0, rsub, a0, bv1);
      st16(act, C_T0 + w * 16 + ln16, 1, rsub, a1, bv1);
    } else {
      int n = w & 3, mt = (w >> 2) & 1;
      bf16x8 wf[12];
#pragma unroll
      for (int kt = 0; kt < 12; ++kt) wf[kt] = w7s[(size_t)(n * 12 + kt) * 64 + lane];
      SB();
      f32x4 v = {};
#pragma unroll
      for (int kt = 0; kt < 12; ++kt) {
        int col = (kt < 8) ? (C_C + kt * 32) : (yR + (kt - 8) * 32);
        v = mfma16(aread(act, mt, col, lane), wf[kt], v);
      }
#pragma unroll
      for (int r = 0; r < 4; ++r) {
        int row = mt * 16 + rsub + r;
        float s = v[r] + (float)*(const __bf16*)(act + act_off(row, C_B7 + n * 16 + ln16));
        *(__bf16*)(act + act_off(row, C_HZP + n * 16 + ln16)) = (__bf16)fmaxf(s, 0.f);
      }
    }
    wg_barrier();

    // ---- C: w0-7 y2; w8-15 mean_p/lv_p + sample zp (prior done)
    if (w < 8) {
      bf16x8 wf[4];
#pragma unroll
      for (int kt = 0; kt < 4; ++kt) wf[kt] = w2p[(size_t)(w * 4 + kt) * 64 + lane];
      SB();
      f32x4 a0 = {}, a1 = {};
#pragma unroll
      for (int kt = 0; kt < 4; ++kt) {
        a0 = mfma16(aread(act, 0, C_T0 + kt * 32, lane), wf[kt], a0);
        a1 = mfma16(aread(act, 1, C_T0 + kt * 32, lane), wf[kt], a1);
      }
      st16(act, C_T1 + w * 16 + ln16, 0, rsub, a0, bv2);
      st16(act, C_T1 + w * 16 + ln16, 1, rsub, a1, bv2);
    } else {
      int n = w & 3, mt = (w >> 2) & 1;
      bf16x8 wm[2], wl[2];
      float ep[4];
#pragma unroll
      for (int kt = 0; kt < 2; ++kt) {
        wm[kt] = w8p[(size_t)(n * 2 + kt) * 64 + lane];
        wl[kt] = w9p[(size_t)(n * 2 + kt) * 64 + lane];
      }
#pragma unroll
      for (int r = 0; r < 4; ++r)
        ep[r] = __builtin_nontemporal_load(
            p.eps_prior + ((size_t)j * BDIM + r0 + mt * 16 + rsub + r) * ZDIM +
            n * 16 + ln16);
      SB();
      f32x4 vm = {}, vl = {};
#pragma unroll
      for (int kt = 0; kt < 2; ++kt) {
        bf16x8 a = aread(act, mt, C_HZP + kt * 32, lane);
        vm = mfma16(a, wm[kt], vm);
        vl = mfma16(a, wl[kt], vl);
      }
#pragma unroll
      for (int r = 0; r < 4; ++r) {
        int row = mt * 16 + rsub + r, col = n * 16 + ln16;
        float mp = fmaxf(vm[r] + bmA, 0.f), lp = fmaxf(vl[r] + blA, 0.f);
        float zp = mp + ep[r] * __expf(0.5f * lp);
        __builtin_nontemporal_store(
            zp, outzp + ((size_t)(r0 + row) * STEPS + j) * ZDIM + col);
      }
    }
    wg_barrier();

    // ---- D: w0-7 y3 -> yW + outy; w8-15 hz partial over [c|yp]
    if (w < 8) {
      bf16x8 wf[4];
#pragma unroll
      for (int kt = 0; kt < 4; ++kt) wf[kt] = w3p[(size_t)(w * 4 + kt) * 64 + lane];
      SB();
      f32x4 a0 = {}, a1 = {};
#pragma unroll
      for (int kt = 0; kt < 4; ++kt) {
        a0 = mfma16(aread(act, 0, C_T1 + kt * 32, lane), wf[kt], a0);
        a1 = mfma16(aread(act, 1, C_T1 + kt * 32, lane), wf[kt], a1);
      }
#pragma unroll
      for (int mt = 0; mt < 2; ++mt) {
        f32x4 vv = mt ? a1 : a0;
#pragma unroll
        for (int r = 0; r < 4; ++r) {
          int row = mt * 16 + rsub + r;
          float yv = fmaxf(vv[r] + bv3, 0.f);
          *(__bf16*)(act + act_off(row, yW + w * 16 + ln16)) = (__bf16)yv;
          __builtin_nontemporal_store(
              yv, outy + ((size_t)(r0 + row) * STEPS + j) * FDIM + w * 16 + ln16);
        }
      }
    } else {
      int a = w - 8, n = a & 3, mt = a >> 2;
      bf16x8 wf[12];
#pragma unroll
      for (int kk = 0; kk < 12; ++kk) {
        int kt = (kk < 8) ? kk : (kk + 4);  // kt 0..7 (c) and 12..15 (yp)
        wf[kk] = w4s[(size_t)(n * 16 + kt) * 64 + lane];
      }
      SB();
      f32x4 v = {};
#pragma unroll
      for (int kk = 0; kk < 12; ++kk) {
        int col = (kk < 8) ? (C_C + kk * 32) : (yR + (kk - 8) * 32);
        v = mfma16(aread(act, mt, col, lane), wf[kk], v);
      }
#pragma unroll
      for (int r = 0; r < 4; ++r)
        fbuf[(mt * 16 + rsub + r) * 64 + n * 16 + ln16] = v[r];
    }
    wg_barrier();

    // ---- E: refill next-step gates prefetch first (stays in flight across
    //      the remaining barriers), then w0-7 hz y-part + fold -> C_HZ
    LDK(0, 0);
    LDK(1, 1);
    LDK(2, 2);
    SB();
    if (w < 8) {
      int n = w & 3, mt = w >> 2;
      bf16x8 wf[4];
#pragma unroll
      for (int kt = 8; kt < 12; ++kt) wf[kt - 8] = w4s[(size_t)(n * 16 + kt) * 64 + lane];
      SB();
      f32x4 v = {};
#pragma unroll
      for (int kt = 8; kt < 12; ++kt)
        v = mfma16(aread(act, mt, yW + (kt - 8) * 32, lane), wf[kt - 8], v);
#pragma unroll
      for (int r = 0; r < 4; ++r) {
        int row = mt * 16 + rsub + r, cc = n * 16 + ln16;
        float s = v[r] + fbuf[row * 64 + cc] +
                  (float)*(const __bf16*)(act + act_off(row, C_B4 + cc));
        *(__bf16*)(act + act_off(row, C_HZ + cc)) = (__bf16)fmaxf(s, 0.f);
      }
    }
    wg_barrier();

    // ---- F: w0-7 mean_j/lv_j + sample z -> outputs + C_Z
    if (w < 8) {
      int n = w & 3, mt = w >> 2;
      bf16x8 wm[2], wl[2];
      float ei[4];
#pragma unroll
      for (int kt = 0; kt < 2; ++kt) {
        wm[kt] = w5p[(size_t)(n * 2 + kt) * 64 + lane];
        wl[kt] = w6p[(size_t)(n * 2 + kt) * 64 + lane];
      }
#pragma unroll
      for (int r = 0; r < 4; ++r)
        ei[r] = __builtin_nontemporal_load(
            p.eps_inf + ((size_t)j * BDIM + r0 + mt * 16 + rsub + r) * ZDIM +
            n * 16 + ln16);
      SB();
      f32x4 vm = {}, vl = {};
#pragma unroll
      for (int kt = 0; kt < 2; ++kt) {
        bf16x8 a = aread(act, mt, C_HZ + kt * 32, lane);
        vm = mfma16(a, wm[kt], vm);
        vl = mfma16(a, wl[kt], vl);
      }
#pragma unroll
      for (int r = 0; r < 4; ++r) {
        int row = mt * 16 + rsub + r, col = n * 16 + ln16;
        float m = fmaxf(vm[r] + bmA, 0.f), l = fmaxf(vl[r] + blA, 0.f);
        float zn = m + ei[r] * __expf(0.5f * l);
        size_t ob = ((size_t)(r0 + row) * STEPS + j) * ZDIM + col;
        __builtin_nontemporal_store(m, outm + ob);
        __builtin_nontemporal_store(l, outl + ob);
        __builtin_nontemporal_store(zn, outz + ob);
        *(__bf16*)(act + act_off(row, C_Z + col)) = (__bf16)zn;
      }
    }
    wg_barrier();
  }
}

extern "C" void kernel_launch(void* const* d_in, const int* in_sizes, int n_in,
                              void* d_out, int out_size, void* d_ws, size_t ws_size,
                              hipStream_t stream) {
  const float* h_i = (const float*)d_in[0];
  const float* input_t = (const float*)d_in[1];
  const float* eps_inf = (const float*)d_in[2];
  const float* eps_prior = (const float*)d_in[3];
  const float* Wx = (const float*)d_in[4];
  const float* Wh = (const float*)d_in[5];
  const float* b_lstm = (const float*)d_in[6];
  const float* w1 = (const float*)d_in[7];  const float* b1 = (const float*)d_in[8];
  const float* w2 = (const float*)d_in[9];  const float* b2 = (const float*)d_in[10];
  const float* w3 = (const float*)d_in[11]; const float* b3 = (const float*)d_in[12];
  const float* w4 = (const float*)d_in[13]; const float* b4 = (const float*)d_in[14];
  const float* w5 = (const float*)d_in[15]; const float* b5 = (const float*)d_in[16];
  const float* w6 = (const float*)d_in[17]; const float* b6 = (const float*)d_in[18];
  const float* w7 = (const float*)d_in[19]; const float* b7 = (const float*)d_in[20];
  const float* w8 = (const float*)d_in[21]; const float* b8 = (const float*)d_in[22];
  const float* w9 = (const float*)d_in[23]; const float* b9 = (const float*)d_in[24];
  const float* alpha = (const float*)d_in[25];
  const float* beta = (const float*)d_in[26];
  const float* mu0 = (const float*)d_in[27];
  __bf16* ws = (__bf16*)d_ws;

  auto S = [](const float* ptr, int row0, int len) {
    PSeg s; s.p = ptr; s.row0 = row0; s.len = len; return s;
  };
  PSeg Zs; Zs.p = nullptr; Zs.row0 = 0; Zs.len = 0;
  auto L = [&](PSeg a, PSeg b, PSeg c, int K, int N, unsigned off) {
    int total = (K / 32) * (N / 16) * 64;
    pack_w<<<(total + 255) / 256, 256, 0, stream>>>(a, b, c, K, N, ws + off);
  };
  L(S(Wx, 0, 64), S(Wx, 320, 128), S(Wh, 0, 256), 448, 1024, PW_GS);  // [z|yp|h]
  L(S(Wx, 64, 256), Zs, Zs, 256, 1024, PW_GHI);
  L(S(w1, 0, 256), Zs, Zs, 256, 128, PW_W1);
  L(S(w2, 0, 128), Zs, Zs, 128, 128, PW_W2);
  L(S(w3, 0, 128), Zs, Zs, 128, 128, PW_W3);
  L(S(w4, 256, 512), Zs, Zs, 512, 64, PW_W4S);  // [c|y|yp]
  L(S(w4, 0, 256), Zs, Zs, 256, 64, PW_W4H);
  L(S(w5, 0, 64), Zs, Zs, 64, 64, PW_W5);
  L(S(w6, 0, 64), Zs, Zs, 64, 64, PW_W6);
  L(S(w7, 256, 384), Zs, Zs, 384, 64, PW_W7S);  // [c|yp]
  L(S(w7, 0, 256), Zs, Zs, 256, 64, PW_W7H);
  L(S(w8, 0, 64), Zs, Zs, 64, 64, PW_W8);
  L(S(w9, 0, 64), Zs, Zs, 64, 64, PW_W9);

  Params p;
  p.h_i = h_i; p.input_t = input_t; p.eps_inf = eps_inf; p.eps_prior = eps_prior;
  p.b_lstm = b_lstm; p.b1 = b1; p.b2 = b2; p.b3 = b3; p.b4 = b4; p.b5 = b5;
  p.b6 = b6; p.b7 = b7; p.b8 = b8; p.b9 = b9;
  p.alpha = alpha; p.beta = beta; p.mu0 = mu0;
  p.wpack = ws;
  p.out = (float*)d_out;

  decoder_main<<<256, 1024, 0, stream>>>(p);
}